// Round 5
// baseline (239.397 us; speedup 1.0000x reference)
//
#include <hip/hip_runtime.h>

constexpr int BATCH = 2048;
constexpr int NHID  = 512;
constexpr int H0    = 256;
constexpr int H1    = 256;
constexpr int S     = 8;    // samples per tile
constexpr int J     = 3;    // tile-slot blocks per parent (grid = 256*J)

// Block (p = blockIdx&255, j = blockIdx>>8) handles tiles j, j+J, ... of
// parent p's group (deterministic ballot-scan list build, R4-verified).
// Wave g -> (pass = g>>1, samples 4*(g&1)..+3): full-depth register GEMV,
// 4 classes/lane (float4 weight rows, ring-8 prefetch), complete logits in
// registers -> wave-local shuffle softmax (NO barriers, no part[] LDS).
__global__ __launch_bounds__(256) void hs_wavelocal(
    const float* __restrict__ x,        // [B, NHID]
    const int*   __restrict__ labels,   // [B]
    const int*   __restrict__ parents,  // [B]
    const float* __restrict__ topW,     // [NHID, H0]
    const float* __restrict__ topb,     // [H0]
    const float* __restrict__ botW,     // [H0, NHID, H1]
    const float* __restrict__ botb,     // [H0, H1]
    float*       __restrict__ out)      // [B]
{
    const int p = blockIdx.x & 255;
    const int j = blockIdx.x >> 8;
    const int t = threadIdx.x;
    const int g = t >> 6;             // wave 0..3
    const int l = t & 63;             // lane
    const int mypass = g >> 1;        // waves 0,1 -> top; 2,3 -> bottom
    const int sb     = (g & 1) * 4;   // my 4 sample slots: sb..sb+3

    __shared__ int   list[BATCH];                   // 8 KB
    __shared__ int   wcnt[4];
    __shared__ __align__(16) float xs[S][NHID];     // 16 KB
    __shared__ float psm[2][S];

    // ---- deterministic ordered list build (ballot prefix scan, R4-verified)
    int running = 0;
    for (int c = 0; c < BATCH; c += 256) {
        const bool match = (parents[c + t] == p);
        const unsigned long long mask = __ballot(match);
        if (l == 0) wcnt[g] = __popcll(mask);
        __syncthreads();
        int off = running;
        for (int w = 0; w < g; ++w) off += wcnt[w];
        if (match)
            list[off + __popcll(mask & ((1ull << l) - 1ull))] = c + t;
        running += wcnt[0] + wcnt[1] + wcnt[2] + wcnt[3];
        __syncthreads();   // wcnt reused next chunk
    }
    const int n = running;
    if (n <= j * S) return;   // uniform exit

    const float* Wbase = mypass ? botW + (size_t)p * NHID * H1 : topW;
    const float4 b4    = mypass ? *(const float4*)(botb + (size_t)p * H1 + 4 * l)
                                : *(const float4*)(topb + 4 * l);

    for (int base = j * S; base < n; base += J * S) {
        const int rem = min(S, n - base);

        // ---- cooperative load of 8 x-rows (padded slots replicate last)
        for (int s = 0; s < S; ++s) {
            const int idx = list[base + min(s, rem - 1)];
            ((float2*)xs[s])[t] = ((const float2*)(x + (size_t)idx * NHID))[t];
        }

        // per-sample softmax targets (wave-uniform scalars)
        int tgts[4];
        #pragma unroll
        for (int si = 0; si < 4; ++si) {
            const int slot = base + min(sb + si, rem - 1);
            tgts[si] = mypass ? labels[list[slot]] : p;
        }
        __syncthreads();   // xs ready

        // ---- full-depth register GEMV: 4 samples, 4 classes/lane
        float4 acc[4];
        #pragma unroll
        for (int si = 0; si < 4; ++si) acc[si] = make_float4(0.f, 0.f, 0.f, 0.f);

        const float* Wp = Wbase + 4 * l;
        float4 ring[8];
        #pragma unroll
        for (int i = 0; i < 8; ++i)
            ring[i] = *(const float4*)(Wp + (size_t)i * H0);

        for (int d = 0; d < NHID; d += 8) {
            #pragma unroll
            for (int h = 0; h < 2; ++h) {
                const int dd = d + 4 * h;
                float4 w0 = ring[4 * h + 0], w1 = ring[4 * h + 1];
                float4 w2 = ring[4 * h + 2], w3 = ring[4 * h + 3];
                if (dd + 8 < NHID) {
                    #pragma unroll
                    for (int i = 0; i < 4; ++i)
                        ring[4 * h + i] =
                            *(const float4*)(Wp + (size_t)(dd + 8 + i) * H0);
                }
                #pragma unroll
                for (int si = 0; si < 4; ++si) {
                    const float4 xv = *(const float4*)&xs[sb + si][dd];
                    float4 a = acc[si];
                    a.x = fmaf(xv.x, w0.x, a.x); a.y = fmaf(xv.x, w0.y, a.y);
                    a.z = fmaf(xv.x, w0.z, a.z); a.w = fmaf(xv.x, w0.w, a.w);
                    a.x = fmaf(xv.y, w1.x, a.x); a.y = fmaf(xv.y, w1.y, a.y);
                    a.z = fmaf(xv.y, w1.z, a.z); a.w = fmaf(xv.y, w1.w, a.w);
                    a.x = fmaf(xv.z, w2.x, a.x); a.y = fmaf(xv.z, w2.y, a.y);
                    a.z = fmaf(xv.z, w2.z, a.z); a.w = fmaf(xv.z, w2.w, a.w);
                    a.x = fmaf(xv.w, w3.x, a.x); a.y = fmaf(xv.w, w3.y, a.y);
                    a.z = fmaf(xv.w, w3.z, a.z); a.w = fmaf(xv.w, w3.w, a.w);
                    acc[si] = a;
                }
            }
        }

        // ---- wave-local softmax per sample (shuffle-only, no barriers)
        #pragma unroll
        for (int si = 0; si < 4; ++si) {
            float4 v = acc[si];
            v.x += b4.x; v.y += b4.y; v.z += b4.z; v.w += b4.w;

            float m = fmaxf(fmaxf(v.x, v.y), fmaxf(v.z, v.w));
            #pragma unroll
            for (int off = 32; off > 0; off >>= 1)
                m = fmaxf(m, __shfl_xor(m, off, 64));

            const float ex = expf(v.x - m), ey = expf(v.y - m);
            const float ez = expf(v.z - m), ew = expf(v.w - m);
            float sum = (ex + ey) + (ez + ew);
            #pragma unroll
            for (int off = 32; off > 0; off >>= 1)
                sum += __shfl_xor(sum, off, 64);

            const int tgt = tgts[si];          // wave-uniform
            const int k   = tgt & 3;
            const float ev = (k == 0) ? ex : (k == 1) ? ey : (k == 2) ? ez : ew;
            if (l == (tgt >> 2))
                psm[mypass][sb + si] = ev / sum;
        }
        __syncthreads();   // psm complete

        if (t < rem) {
            const int idx = list[base + t];
            out[idx] = psm[0][t] * psm[1][t];
        }
        __syncthreads();   // xs/psm safe to overwrite next tile
    }
}

extern "C" void kernel_launch(void* const* d_in, const int* in_sizes, int n_in,
                              void* d_out, int out_size, void* d_ws, size_t ws_size,
                              hipStream_t stream) {
    const float* x       = (const float*)d_in[0];
    const int*   labels  = (const int*)  d_in[1];
    const int*   parents = (const int*)  d_in[2];
    const float* topW    = (const float*)d_in[3];
    const float* topb    = (const float*)d_in[4];
    const float* botW    = (const float*)d_in[5];
    const float* botb    = (const float*)d_in[6];
    float*       out     = (float*)d_out;

    hs_wavelocal<<<H0 * J, 256, 0, stream>>>(x, labels, parents,
                                             topW, topb, botW, botb, out);
}

// Round 6
// 227.856 us; speedup vs baseline: 1.0507x; 1.0507x over previous
//
#include <hip/hip_runtime.h>

constexpr int BATCH = 2048;
constexpr int NHID  = 512;
constexpr int H0    = 256;
constexpr int H1    = 256;
constexpr int S     = 8;    // samples per tile
constexpr int J     = 3;    // tile-slot blocks per parent (grid = 256*J)

// Block bid -> (p = bid/J, j = bid%J): handles tiles j, j+J, ... of parent
// p's group. 128 threads = 2 waves: wave 0 = top pass, wave 1 = bottom pass,
// each wave computing ALL 8 samples of the tile (acc[8] float4 = 128 FMA per
// float4 weight load -> ring use-distance ~512 cyc, covers L3 latency).
// List build: R4-verified ballot scan (128-thread variant). Softmax:
// R5-verified wave-local shuffle reduction.
__global__ __launch_bounds__(128) void hs_8s(
    const float* __restrict__ x,        // [B, NHID]
    const int*   __restrict__ labels,   // [B]
    const int*   __restrict__ parents,  // [B]
    const float* __restrict__ topW,     // [NHID, H0]
    const float* __restrict__ topb,     // [H0]
    const float* __restrict__ botW,     // [H0, NHID, H1]
    const float* __restrict__ botb,     // [H0, H1]
    float*       __restrict__ out)      // [B]
{
    const int p = blockIdx.x / J;
    const int j = blockIdx.x % J;
    const int t = threadIdx.x;        // 0..127
    const int g = t >> 6;             // wave 0 = top, wave 1 = bottom
    const int l = t & 63;

    __shared__ int   list[BATCH];                   // 8 KB
    __shared__ int   wcnt[2];
    __shared__ __align__(16) float xs[S][NHID];     // 16 KB
    __shared__ float psm[2][S];

    // ---- deterministic ordered list build (ballot prefix scan)
    int running = 0;
    for (int c = 0; c < BATCH; c += 128) {
        const bool match = (parents[c + t] == p);
        const unsigned long long mask = __ballot(match);
        if (l == 0) wcnt[g] = __popcll(mask);
        __syncthreads();
        const int off = running + (g ? wcnt[0] : 0);
        if (match)
            list[off + __popcll(mask & ((1ull << l) - 1ull))] = c + t;
        running += wcnt[0] + wcnt[1];
        __syncthreads();   // wcnt reused next chunk
    }
    const int n = running;
    if (n <= j * S) return;   // uniform exit

    const float* Wbase = g ? botW + (size_t)p * NHID * H1 : topW;
    const float4 b4    = g ? *(const float4*)(botb + (size_t)p * H1 + 4 * l)
                           : *(const float4*)(topb + 4 * l);

    for (int base = j * S; base < n; base += J * S) {
        const int rem = min(S, n - base);

        // ---- stage 8 x-rows (padded slots replicate last); 1 float4/thr/row
        for (int s = 0; s < S; ++s) {
            const int idx = list[base + min(s, rem - 1)];
            ((float4*)xs[s])[t] = ((const float4*)(x + (size_t)idx * NHID))[t];
        }

        // per-sample softmax targets (wave-uniform)
        int tgts[S];
        #pragma unroll
        for (int s = 0; s < S; ++s) {
            const int slot = base + min(s, rem - 1);
            tgts[s] = g ? labels[list[slot]] : p;
        }
        __syncthreads();   // xs ready

        // ---- full-depth register GEMV: 8 samples, 4 classes/lane
        float4 acc[S];
        #pragma unroll
        for (int s = 0; s < S; ++s) acc[s] = make_float4(0.f, 0.f, 0.f, 0.f);

        const float* Wp = Wbase + 4 * l;
        float4 ring[8];
        #pragma unroll
        for (int i = 0; i < 8; ++i)
            ring[i] = *(const float4*)(Wp + (size_t)i * H0);

        for (int d = 0; d < NHID; d += 8) {
            #pragma unroll
            for (int h = 0; h < 2; ++h) {
                const int dd = d + 4 * h;
                const float4 w0 = ring[4 * h + 0], w1 = ring[4 * h + 1];
                const float4 w2 = ring[4 * h + 2], w3 = ring[4 * h + 3];
                if (dd + 8 < NHID) {
                    #pragma unroll
                    for (int i = 0; i < 4; ++i)
                        ring[4 * h + i] =
                            *(const float4*)(Wp + (size_t)(dd + 8 + i) * H0);
                }
                #pragma unroll
                for (int s = 0; s < S; ++s) {
                    const float4 xv = *(const float4*)&xs[s][dd];  // broadcast
                    float4 a = acc[s];
                    a.x = fmaf(xv.x, w0.x, a.x); a.y = fmaf(xv.x, w0.y, a.y);
                    a.z = fmaf(xv.x, w0.z, a.z); a.w = fmaf(xv.x, w0.w, a.w);
                    a.x = fmaf(xv.y, w1.x, a.x); a.y = fmaf(xv.y, w1.y, a.y);
                    a.z = fmaf(xv.y, w1.z, a.z); a.w = fmaf(xv.y, w1.w, a.w);
                    a.x = fmaf(xv.z, w2.x, a.x); a.y = fmaf(xv.z, w2.y, a.y);
                    a.z = fmaf(xv.z, w2.z, a.z); a.w = fmaf(xv.z, w2.w, a.w);
                    a.x = fmaf(xv.w, w3.x, a.x); a.y = fmaf(xv.w, w3.y, a.y);
                    a.z = fmaf(xv.w, w3.z, a.z); a.w = fmaf(xv.w, w3.w, a.w);
                    acc[s] = a;
                }
            }
        }

        // ---- wave-local softmax per sample (R5-verified)
        #pragma unroll
        for (int s = 0; s < S; ++s) {
            float4 v = acc[s];
            v.x += b4.x; v.y += b4.y; v.z += b4.z; v.w += b4.w;

            float m = fmaxf(fmaxf(v.x, v.y), fmaxf(v.z, v.w));
            #pragma unroll
            for (int off = 32; off > 0; off >>= 1)
                m = fmaxf(m, __shfl_xor(m, off, 64));

            const float ex = expf(v.x - m), ey = expf(v.y - m);
            const float ez = expf(v.z - m), ew = expf(v.w - m);
            float sum = (ex + ey) + (ez + ew);
            #pragma unroll
            for (int off = 32; off > 0; off >>= 1)
                sum += __shfl_xor(sum, off, 64);

            const int tgt = tgts[s];           // wave-uniform
            const int k   = tgt & 3;
            const float ev = (k == 0) ? ex : (k == 1) ? ey : (k == 2) ? ez : ew;
            if (l == (tgt >> 2))
                psm[g][s] = ev / sum;
        }
        __syncthreads();   // psm complete

        if (t < rem) {
            const int idx = list[base + t];
            out[idx] = psm[0][t] * psm[1][t];
        }
        __syncthreads();   // xs/psm safe to overwrite next tile
    }
}

extern "C" void kernel_launch(void* const* d_in, const int* in_sizes, int n_in,
                              void* d_out, int out_size, void* d_ws, size_t ws_size,
                              hipStream_t stream) {
    const float* x       = (const float*)d_in[0];
    const int*   labels  = (const int*)  d_in[1];
    const int*   parents = (const int*)  d_in[2];
    const float* topW    = (const float*)d_in[3];
    const float* topb    = (const float*)d_in[4];
    const float* botW    = (const float*)d_in[5];
    const float* botb    = (const float*)d_in[6];
    float*       out     = (float*)d_out;

    hs_8s<<<H0 * J, 128, 0, stream>>>(x, labels, parents,
                                      topW, topb, botW, botb, out);
}